// Round 18
// baseline (104.498 us; speedup 1.0000x reference)
//
#include <hip/hip_runtime.h>
#include <math.h>
#include <float.h>

#define B_    4
#define N_    2048
#define M_    8192
#define CIN_  512
#define COUT_ 256

typedef __attribute__((ext_vector_type(8))) short short8v;   // 8 bf16
typedef __attribute__((ext_vector_type(4))) float f32x4;

// ---------------------------------------------------------------------------
// d_ws handoff: producers store system-scope (sc0 sc1 -> L3 coherence point);
// one inv_kernel invalidates XCD L1/L2 before the consumer, so consumers use
// normal cached loads. (Round 4/8/9 lessons.)
// ---------------------------------------------------------------------------
__device__ __forceinline__ void ws_store_f32(float* p, float v) {
    __hip_atomic_store((unsigned int*)p, __float_as_uint(v),
                       __ATOMIC_RELAXED, __HIP_MEMORY_SCOPE_SYSTEM);
}
__device__ __forceinline__ void ws_store_u32(int* p, int v) {
    __hip_atomic_store((unsigned int*)p, (unsigned int)v,
                       __ATOMIC_RELAXED, __HIP_MEMORY_SCOPE_SYSTEM);
}

__global__ __launch_bounds__(64) void inv_kernel() {
    asm volatile("buffer_inv sc0 sc1" ::: "memory");
}

__device__ __forceinline__ unsigned short f2bf(float f) {   // RNE f32->bf16
    unsigned u = __float_as_uint(f);
    u += 0x7fffu + ((u >> 16) & 1u);
    return (unsigned short)(u >> 16);
}

// ---------------------------------------------------------------------------
// bf16-MFMA GEMM body (round-11, validated): 64c x 128m block tile, 4 waves,
// wave tile 32x64 (acc[2][4]), BK=32, fp32->bf16 RNE staging, K-step register
// prefetch. MODE 0 (up): BN+ReLU -> LDS transpose -> sc f1t[n][c].
// MODE 1 (lat): BN+ReLU + 3-NN interp add; nnrec prefetched pre-K-loop.
// ---------------------------------------------------------------------------
template<int K, int MODE>
__device__ __forceinline__ void gemm_body(
    char* raw, int b, int c0, int m0,
    const float* __restrict__ X, const float* __restrict__ W,
    const float* __restrict__ gam, const float* __restrict__ bet,
    const float* __restrict__ mu, const float* __restrict__ var,
    float* __restrict__ dst,
    const float* __restrict__ f1t, const float* __restrict__ nnrec, int Mdim)
{
    char* Ab = raw;            // A: [64 c][40 bf16]   row stride 80 B
    char* Bb = raw + 5120;     // B: [128 m][40 bf16]

    const int tid = threadIdx.x;
    const int l  = tid & 63;
    const int wv = tid >> 6;
    const int wc = wv & 1, wn = wv >> 1;

    f32x4 acc[2][4];
    #pragma unroll
    for (int i = 0; i < 2; ++i)
        #pragma unroll
        for (int j = 0; j < 4; ++j)
            acc[i][j] = (f32x4){0.f, 0.f, 0.f, 0.f};

    const int ksA = tid & 7;
    const int crA = tid >> 3;
    const int kqB = tid >> 5;
    const int mlB = tid & 31;

    float4 ra[4]; float2 rb[4];
    if constexpr (MODE == 1) {
        #pragma unroll
        for (int ni = 0; ni < 4; ++ni) {
            int mg = m0 + wn * 64 + ni * 16 + (l & 15);
            const float* rp = nnrec + ((size_t)b * M_ + mg) * 8;
            ra[ni] = *(const float4*)rp;
            rb[ni] = *(const float2*)(rp + 4);
        }
    }

    float4 wreg[2];
    float  xreg[4][4];
    #pragma unroll
    for (int r = 0; r < 2; ++r)
        wreg[r] = *(const float4*)(W + (size_t)(c0 + crA + 32 * r) * K + ksA * 4);
    #pragma unroll
    for (int jj = 0; jj < 4; ++jj) {
        const float* xp = X + ((size_t)b * K + kqB * 4) * Mdim + m0 + mlB + 32 * jj;
        xreg[jj][0] = xp[0];
        xreg[jj][1] = xp[(size_t)Mdim];
        xreg[jj][2] = xp[(size_t)2 * Mdim];
        xreg[jj][3] = xp[(size_t)3 * Mdim];
    }

    for (int kc = 0; kc < K; kc += 32) {
        #pragma unroll
        for (int r = 0; r < 2; ++r) {
            unsigned lo = f2bf(wreg[r].x) | ((unsigned)f2bf(wreg[r].y) << 16);
            unsigned hi = f2bf(wreg[r].z) | ((unsigned)f2bf(wreg[r].w) << 16);
            *(uint2*)(Ab + (crA + 32 * r) * 80 + ksA * 8) = make_uint2(lo, hi);
        }
        #pragma unroll
        for (int jj = 0; jj < 4; ++jj) {
            unsigned lo = f2bf(xreg[jj][0]) | ((unsigned)f2bf(xreg[jj][1]) << 16);
            unsigned hi = f2bf(xreg[jj][2]) | ((unsigned)f2bf(xreg[jj][3]) << 16);
            *(uint2*)(Bb + (mlB + 32 * jj) * 80 + kqB * 8) = make_uint2(lo, hi);
        }
        if (kc + 32 < K) {
            #pragma unroll
            for (int r = 0; r < 2; ++r)
                wreg[r] = *(const float4*)(W + (size_t)(c0 + crA + 32 * r) * K + (kc + 32) + ksA * 4);
            #pragma unroll
            for (int jj = 0; jj < 4; ++jj) {
                const float* xp = X + ((size_t)b * K + (kc + 32) + kqB * 4) * Mdim + m0 + mlB + 32 * jj;
                xreg[jj][0] = xp[0];
                xreg[jj][1] = xp[(size_t)Mdim];
                xreg[jj][2] = xp[(size_t)2 * Mdim];
                xreg[jj][3] = xp[(size_t)3 * Mdim];
            }
        }
        __syncthreads();
        short8v a[2], bfv[4];
        #pragma unroll
        for (int ci = 0; ci < 2; ++ci)
            a[ci] = *(const short8v*)(Ab + (wc * 32 + ci * 16 + (l & 15)) * 80 + (l >> 4) * 16);
        #pragma unroll
        for (int ni = 0; ni < 4; ++ni)
            bfv[ni] = *(const short8v*)(Bb + (wn * 64 + ni * 16 + (l & 15)) * 80 + (l >> 4) * 16);
        #pragma unroll
        for (int ci = 0; ci < 2; ++ci)
            #pragma unroll
            for (int ni = 0; ni < 4; ++ni)
                acc[ci][ni] = __builtin_amdgcn_mfma_f32_16x16x32_bf16(
                    a[ci], bfv[ni], acc[ci][ni], 0, 0, 0);
        __syncthreads();
    }

    const int lc = (l >> 4) * 4;
    float scA[2][4], shA[2][4];
    #pragma unroll
    for (int ci = 0; ci < 2; ++ci)
        #pragma unroll
        for (int r = 0; r < 4; ++r) {
            int c = c0 + wc * 32 + ci * 16 + lc + r;
            float sc = gam[c] / sqrtf(var[c] + 1e-5f);
            scA[ci][r] = sc;
            shA[ci][r] = bet[c] - mu[c] * sc;
        }

    if constexpr (MODE == 0) {
        float* S = (float*)raw;   // [64][66] f32
        #pragma unroll
        for (int h = 0; h < 2; ++h) {
            if (wn == h) {
                #pragma unroll
                for (int ni = 0; ni < 4; ++ni)
                    #pragma unroll
                    for (int ci = 0; ci < 2; ++ci)
                        #pragma unroll
                        for (int r = 0; r < 4; ++r)
                            S[(ni * 16 + (l & 15)) * 66 + wc * 32 + ci * 16 + lc + r] =
                                fmaxf(acc[ci][ni][r] * scA[ci][r] + shA[ci][r], 0.f);
            }
            __syncthreads();
            #pragma unroll
            for (int i = 0; i < 16; ++i) {
                int e = tid + i * 256;
                int row = e >> 6, c = e & 63;
                ws_store_f32(dst + ((size_t)b * N_ + m0 + h * 64 + row) * COUT_ + c0 + c,
                             S[row * 66 + c]);
            }
            __syncthreads();
        }
    } else {
        #pragma unroll
        for (int ni = 0; ni < 4; ++ni) {
            int mg = m0 + wn * 64 + ni * 16 + (l & 15);
            int   i0 = __float_as_int(ra[ni].x);
            int   i1 = __float_as_int(ra[ni].y);
            int   i2 = __float_as_int(ra[ni].z);
            float w0 = ra[ni].w, w1 = rb[ni].x, w2 = rb[ni].y;
            const float4* g0 = (const float4*)(f1t + ((size_t)b * N_ + i0) * COUT_ + c0 + wc * 32 + lc);
            const float4* g1 = (const float4*)(f1t + ((size_t)b * N_ + i1) * COUT_ + c0 + wc * 32 + lc);
            const float4* g2 = (const float4*)(f1t + ((size_t)b * N_ + i2) * COUT_ + c0 + wc * 32 + lc);
            #pragma unroll
            for (int ci = 0; ci < 2; ++ci) {
                float4 G0 = g0[ci * 4];
                float4 G1 = g1[ci * 4];
                float4 G2 = g2[ci * 4];
                const float* f0 = (const float*)&G0;
                const float* f1 = (const float*)&G1;
                const float* f2 = (const float*)&G2;
                #pragma unroll
                for (int r = 0; r < 4; ++r) {
                    float v = fmaxf(acc[ci][ni][r] * scA[ci][r] + shA[ci][r], 0.f);
                    v = fmaf(w0, f0[r], v);
                    v = fmaf(w1, f1[r], v);
                    v = fmaf(w2, f2[r], v);
                    int c = c0 + wc * 32 + ci * 16 + lc + r;
                    dst[((size_t)b * COUT_ + c) * M_ + mg] = v;
                }
            }
        }
    }
}

__global__ __launch_bounds__(256) void up_kernel(
    const float* __restrict__ x1, const float* __restrict__ w_up,
    const float* __restrict__ g_up, const float* __restrict__ b_up,
    const float* __restrict__ m_up, const float* __restrict__ v_up,
    float* __restrict__ f1t)
{
    __shared__ float4 raw4[1056];
    gemm_body<CIN_, 0>((char*)raw4, blockIdx.z, blockIdx.y * 64, blockIdx.x * 128,
                       x1, w_up, g_up, b_up, m_up, v_up, f1t,
                       nullptr, nullptr, N_);
}

__global__ __launch_bounds__(256) void lat_kernel(
    const float* __restrict__ x2, const float* __restrict__ w_lat,
    const float* __restrict__ g_lat, const float* __restrict__ b_lat,
    const float* __restrict__ m_lat, const float* __restrict__ v_lat,
    const float* __restrict__ f1t, const float* __restrict__ nnrec,
    float* __restrict__ out0)
{
    __shared__ float4 raw4[960];
    gemm_body<COUT_, 1>((char*)raw4, blockIdx.z, blockIdx.y * 64, blockIdx.x * 128,
                        x2, w_lat, g_lat, b_lat, m_lat, v_lat, out0,
                        f1t, nnrec, M_);
}

// ---------------------------------------------------------------------------
// three_nn (round-17 structure, re-shaped for occupancy): 16 lanes/query over
// disjoint 128-candidate segments (was 8x256); 512-thread blocks keep the
// same 33KB LDS but host 8 waves -> 4 blocks/CU = 32 waves/CU capacity
// (round-17 measured Occupancy 29%, VALUBusy 73% -> latency headroom).
// Chunks of 8 read as b128 with register ping-pong prefetch. Scan insert is
// a 13-op min/max network + index selects — PROVEN identical to the strict-<
// stable bubble insert (all tie cases checked). Butterfly merge (4 stages)
// keeps full lexicographic (d2, idx). d^2 bits identical to the validated
// formula:
//   s = fma(z,z, fma(y,y, x*x)); dot likewise; d2 = max(fma(-2,dot,s2+s1),0)
// ---------------------------------------------------------------------------
__device__ __forceinline__ void lex_insert(float e, int j,
    float& D0, float& D1, float& D2, int& I0, int& I1, int& I2)
{
    bool l0 = (e < D0) || (e == D0 && j < I0);
    bool l1 = (e < D1) || (e == D1 && j < I1);
    bool l2 = (e < D2) || (e == D2 && j < I2);
    if (l2) {
        if (l0)      { D2=D1; I2=I1; D1=D0; I1=I0; D0=e; I0=j; }
        else if (l1) { D2=D1; I2=I1; D1=e;  I1=j; }
        else         { D2=e;  I2=j; }
    }
}

// 13-op insert: values via min/max network, indices via 3 cmp + 5 selects.
// Exactly equivalent to strict-< stable insert (ascending-scan stability).
__device__ __forceinline__ void mm_insert(float d, int iv,
    float& D0, float& D1, float& D2, int& I0, int& I1, int& I2)
{
    bool c1 = d < D0;
    bool c2 = d < D1;
    bool c3 = d < D2;
    int nI2 = c3 ? (c2 ? I1 : iv) : I2;
    int nI1 = c2 ? (c1 ? I0 : iv) : I1;
    int nI0 = c1 ? iv : I0;
    float t   = fmaxf(D0, d);
    float nD0 = fminf(D0, d);
    float nD1 = fminf(D1, t);
    float t2  = fmaxf(D1, t);
    float nD2 = fminf(D2, t2);
    D0 = nD0; D1 = nD1; D2 = nD2;
    I0 = nI0; I1 = nI1; I2 = nI2;
}

__global__ __launch_bounds__(512) void three_nn_kernel(
    const float* __restrict__ p1, const float* __restrict__ p2,
    float* __restrict__ nnrec, float* __restrict__ out1)
{
    __shared__ float4 P[16][129];   // 16 segments x 128 (+1 row pad)
    const int b = blockIdx.y;
    const int tid = threadIdx.x;
    #pragma unroll
    for (int r = 0; r < 4; ++r) {
        int n = r * 512 + tid;
        float x = p1[((size_t)(b*N_)+n)*3 + 0];
        float y = p1[((size_t)(b*N_)+n)*3 + 1];
        float z = p1[((size_t)(b*N_)+n)*3 + 2];
        float t = x * x;
        t = fmaf(y, y, t);
        t = fmaf(z, z, t);
        P[n >> 7][n & 127] = make_float4(x, y, z, t);
    }
    __syncthreads();

    const int m = blockIdx.x * 32 + (tid >> 4);
    const int s = tid & 15;
    const size_t pbase = ((size_t)(b*M_) + m) * 3;
    const float qx = p2[pbase+0], qy = p2[pbase+1], qz = p2[pbase+2];
    float s2 = qx * qx;
    s2 = fmaf(qy, qy, s2);
    s2 = fmaf(qz, qz, s2);

    float D0 = FLT_MAX, D1 = FLT_MAX, D2 = FLT_MAX;
    int   I0 = 0x7fffffff, I1 = 0x7fffffff, I2 = 0x7fffffff;
    const int base = s * 128;
    const float4* Ps = &P[s][0];

    float4 ca[8], cb[8];
    #pragma unroll
    for (int u = 0; u < 8; ++u) ca[u] = Ps[u];

    #define PROC(CV, IB)                                                     \
        {                                                                    \
            float d[8];                                                      \
            _Pragma("unroll")                                                \
            for (int u = 0; u < 8; ++u) {                                    \
                float dot = qx * CV[u].x;                                    \
                dot = fmaf(qy, CV[u].y, dot);                                \
                dot = fmaf(qz, CV[u].z, dot);                                \
                float d2 = fmaf(-2.0f, dot, s2 + CV[u].w);                   \
                d[u] = fmaxf(d2, 0.0f);                                      \
            }                                                                \
            _Pragma("unroll")                                                \
            for (int u = 0; u < 8; ++u)                                      \
                mm_insert(d[u], (IB) + u, D0, D1, D2, I0, I1, I2);           \
        }

    for (int j = 0; j < 16; j += 2) {
        #pragma unroll
        for (int u = 0; u < 8; ++u) cb[u] = Ps[(j + 1) * 8 + u];
        PROC(ca, base + j * 8);
        if (j + 2 < 16) {
            #pragma unroll
            for (int u = 0; u < 8; ++u) ca[u] = Ps[(j + 2) * 8 + u];
        }
        PROC(cb, base + (j + 1) * 8);
    }
    #undef PROC

    #pragma unroll
    for (int st = 1; st <= 8; st <<= 1) {
        float E0 = __shfl_xor(D0, st), E1 = __shfl_xor(D1, st), E2 = __shfl_xor(D2, st);
        int   J0 = __shfl_xor(I0, st), J1 = __shfl_xor(I1, st), J2 = __shfl_xor(I2, st);
        lex_insert(E0, J0, D0, D1, D2, I0, I1, I2);
        lex_insert(E1, J1, D0, D1, D2, I0, I1, I2);
        lex_insert(E2, J2, D0, D1, D2, I0, I1, I2);
    }
    if (s == 0) {
        float r0 = 1.0f / (D0 + 1e-8f);
        float r1 = 1.0f / (D1 + 1e-8f);
        float r2 = 1.0f / (D2 + 1e-8f);
        float sum = (r0 + r1) + r2;
        float* rp = nnrec + ((size_t)(b*M_) + m) * 8;
        ws_store_u32((int*)rp + 0, I0);
        ws_store_u32((int*)rp + 1, I1);
        ws_store_u32((int*)rp + 2, I2);
        ws_store_f32(rp + 3, r0 / sum);
        ws_store_f32(rp + 4, r1 / sum);
        ws_store_f32(rp + 5, r2 / sum);
        size_t o = ((size_t)(b*M_) + m) * 3;
        out1[o+0] = qx; out1[o+1] = qy; out1[o+2] = qz;
    }
}

// ---------------------------------------------------------------------------
extern "C" void kernel_launch(void* const* d_in, const int* in_sizes, int n_in,
                              void* d_out, int out_size, void* d_ws, size_t ws_size,
                              hipStream_t stream)
{
    (void)in_sizes; (void)n_in; (void)out_size; (void)ws_size;

    const float* x1    = (const float*)d_in[0];
    const float* p1    = (const float*)d_in[1];
    const float* x2    = (const float*)d_in[2];
    const float* p2    = (const float*)d_in[3];
    const float* w_up  = (const float*)d_in[4];
    const float* g_up  = (const float*)d_in[5];
    const float* b_up  = (const float*)d_in[6];
    const float* m_up  = (const float*)d_in[7];
    const float* v_up  = (const float*)d_in[8];
    const float* w_lat = (const float*)d_in[9];
    const float* g_lat = (const float*)d_in[10];
    const float* b_lat = (const float*)d_in[11];
    const float* m_lat = (const float*)d_in[12];
    const float* v_lat = (const float*)d_in[13];

    float* out0 = (float*)d_out;
    float* out1 = out0 + (size_t)B_ * COUT_ * M_;   // p2 passthrough

    // workspace layout: f1t (8 MB) | nnrec (1 MB, 8 floats per query)
    float* f1t   = (float*)d_ws;
    float* nnrec = f1t + (size_t)B_ * N_ * COUT_;

    up_kernel<<<dim3(N_ / 128, COUT_ / 64, B_), 256, 0, stream>>>(
        x1, w_up, g_up, b_up, m_up, v_up, f1t);

    three_nn_kernel<<<dim3(M_ / 32, B_), 512, 0, stream>>>(
        p1, p2, nnrec, out1);

    inv_kernel<<<dim3(512), 64, 0, stream>>>();

    lat_kernel<<<dim3(M_ / 128, COUT_ / 64, B_), 256, 0, stream>>>(
        x2, w_lat, g_lat, b_lat, m_lat, v_lat, f1t, nnrec, out0);
}

// Round 19
// 94.034 us; speedup vs baseline: 1.1113x; 1.1113x over previous
//
#include <hip/hip_runtime.h>
#include <math.h>
#include <float.h>

#define B_    4
#define N_    2048
#define M_    8192
#define CIN_  512
#define COUT_ 256

typedef __attribute__((ext_vector_type(8))) short short8v;   // 8 bf16
typedef __attribute__((ext_vector_type(4))) float f32x4;

// ---------------------------------------------------------------------------
// d_ws handoff: producers store system-scope (sc0 sc1 -> L3 coherence point);
// one inv_kernel invalidates XCD L1/L2 before the consumer, so consumers use
// normal cached loads. (Round 4/8/9 lessons.)
// ---------------------------------------------------------------------------
__device__ __forceinline__ void ws_store_f32(float* p, float v) {
    __hip_atomic_store((unsigned int*)p, __float_as_uint(v),
                       __ATOMIC_RELAXED, __HIP_MEMORY_SCOPE_SYSTEM);
}
__device__ __forceinline__ void ws_store_u32(int* p, int v) {
    __hip_atomic_store((unsigned int*)p, (unsigned int)v,
                       __ATOMIC_RELAXED, __HIP_MEMORY_SCOPE_SYSTEM);
}

__global__ __launch_bounds__(64) void inv_kernel() {
    asm volatile("buffer_inv sc0 sc1" ::: "memory");
}

__device__ __forceinline__ unsigned short f2bf(float f) {   // RNE f32->bf16
    unsigned u = __float_as_uint(f);
    u += 0x7fffu + ((u >> 16) & 1u);
    return (unsigned short)(u >> 16);
}

// ---------------------------------------------------------------------------
// bf16-MFMA GEMM body (round-11, validated): 64c x 128m block tile, 4 waves,
// wave tile 32x64 (acc[2][4]), BK=32, fp32->bf16 RNE staging, K-step register
// prefetch. MODE 0 (up): BN+ReLU -> LDS transpose -> sc f1t[n][c].
// MODE 1 (lat): BN+ReLU + 3-NN interp add; nnrec prefetched pre-K-loop.
// ---------------------------------------------------------------------------
template<int K, int MODE>
__device__ __forceinline__ void gemm_body(
    char* raw, int b, int c0, int m0,
    const float* __restrict__ X, const float* __restrict__ W,
    const float* __restrict__ gam, const float* __restrict__ bet,
    const float* __restrict__ mu, const float* __restrict__ var,
    float* __restrict__ dst,
    const float* __restrict__ f1t, const float* __restrict__ nnrec, int Mdim)
{
    char* Ab = raw;            // A: [64 c][40 bf16]   row stride 80 B
    char* Bb = raw + 5120;     // B: [128 m][40 bf16]

    const int tid = threadIdx.x;
    const int l  = tid & 63;
    const int wv = tid >> 6;
    const int wc = wv & 1, wn = wv >> 1;

    f32x4 acc[2][4];
    #pragma unroll
    for (int i = 0; i < 2; ++i)
        #pragma unroll
        for (int j = 0; j < 4; ++j)
            acc[i][j] = (f32x4){0.f, 0.f, 0.f, 0.f};

    const int ksA = tid & 7;
    const int crA = tid >> 3;
    const int kqB = tid >> 5;
    const int mlB = tid & 31;

    float4 ra[4]; float2 rb[4];
    if constexpr (MODE == 1) {
        #pragma unroll
        for (int ni = 0; ni < 4; ++ni) {
            int mg = m0 + wn * 64 + ni * 16 + (l & 15);
            const float* rp = nnrec + ((size_t)b * M_ + mg) * 8;
            ra[ni] = *(const float4*)rp;
            rb[ni] = *(const float2*)(rp + 4);
        }
    }

    float4 wreg[2];
    float  xreg[4][4];
    #pragma unroll
    for (int r = 0; r < 2; ++r)
        wreg[r] = *(const float4*)(W + (size_t)(c0 + crA + 32 * r) * K + ksA * 4);
    #pragma unroll
    for (int jj = 0; jj < 4; ++jj) {
        const float* xp = X + ((size_t)b * K + kqB * 4) * Mdim + m0 + mlB + 32 * jj;
        xreg[jj][0] = xp[0];
        xreg[jj][1] = xp[(size_t)Mdim];
        xreg[jj][2] = xp[(size_t)2 * Mdim];
        xreg[jj][3] = xp[(size_t)3 * Mdim];
    }

    for (int kc = 0; kc < K; kc += 32) {
        #pragma unroll
        for (int r = 0; r < 2; ++r) {
            unsigned lo = f2bf(wreg[r].x) | ((unsigned)f2bf(wreg[r].y) << 16);
            unsigned hi = f2bf(wreg[r].z) | ((unsigned)f2bf(wreg[r].w) << 16);
            *(uint2*)(Ab + (crA + 32 * r) * 80 + ksA * 8) = make_uint2(lo, hi);
        }
        #pragma unroll
        for (int jj = 0; jj < 4; ++jj) {
            unsigned lo = f2bf(xreg[jj][0]) | ((unsigned)f2bf(xreg[jj][1]) << 16);
            unsigned hi = f2bf(xreg[jj][2]) | ((unsigned)f2bf(xreg[jj][3]) << 16);
            *(uint2*)(Bb + (mlB + 32 * jj) * 80 + kqB * 8) = make_uint2(lo, hi);
        }
        if (kc + 32 < K) {
            #pragma unroll
            for (int r = 0; r < 2; ++r)
                wreg[r] = *(const float4*)(W + (size_t)(c0 + crA + 32 * r) * K + (kc + 32) + ksA * 4);
            #pragma unroll
            for (int jj = 0; jj < 4; ++jj) {
                const float* xp = X + ((size_t)b * K + (kc + 32) + kqB * 4) * Mdim + m0 + mlB + 32 * jj;
                xreg[jj][0] = xp[0];
                xreg[jj][1] = xp[(size_t)Mdim];
                xreg[jj][2] = xp[(size_t)2 * Mdim];
                xreg[jj][3] = xp[(size_t)3 * Mdim];
            }
        }
        __syncthreads();
        short8v a[2], bfv[4];
        #pragma unroll
        for (int ci = 0; ci < 2; ++ci)
            a[ci] = *(const short8v*)(Ab + (wc * 32 + ci * 16 + (l & 15)) * 80 + (l >> 4) * 16);
        #pragma unroll
        for (int ni = 0; ni < 4; ++ni)
            bfv[ni] = *(const short8v*)(Bb + (wn * 64 + ni * 16 + (l & 15)) * 80 + (l >> 4) * 16);
        #pragma unroll
        for (int ci = 0; ci < 2; ++ci)
            #pragma unroll
            for (int ni = 0; ni < 4; ++ni)
                acc[ci][ni] = __builtin_amdgcn_mfma_f32_16x16x32_bf16(
                    a[ci], bfv[ni], acc[ci][ni], 0, 0, 0);
        __syncthreads();
    }

    const int lc = (l >> 4) * 4;
    float scA[2][4], shA[2][4];
    #pragma unroll
    for (int ci = 0; ci < 2; ++ci)
        #pragma unroll
        for (int r = 0; r < 4; ++r) {
            int c = c0 + wc * 32 + ci * 16 + lc + r;
            float sc = gam[c] / sqrtf(var[c] + 1e-5f);
            scA[ci][r] = sc;
            shA[ci][r] = bet[c] - mu[c] * sc;
        }

    if constexpr (MODE == 0) {
        float* S = (float*)raw;   // [64][66] f32
        #pragma unroll
        for (int h = 0; h < 2; ++h) {
            if (wn == h) {
                #pragma unroll
                for (int ni = 0; ni < 4; ++ni)
                    #pragma unroll
                    for (int ci = 0; ci < 2; ++ci)
                        #pragma unroll
                        for (int r = 0; r < 4; ++r)
                            S[(ni * 16 + (l & 15)) * 66 + wc * 32 + ci * 16 + lc + r] =
                                fmaxf(acc[ci][ni][r] * scA[ci][r] + shA[ci][r], 0.f);
            }
            __syncthreads();
            #pragma unroll
            for (int i = 0; i < 16; ++i) {
                int e = tid + i * 256;
                int row = e >> 6, c = e & 63;
                ws_store_f32(dst + ((size_t)b * N_ + m0 + h * 64 + row) * COUT_ + c0 + c,
                             S[row * 66 + c]);
            }
            __syncthreads();
        }
    } else {
        #pragma unroll
        for (int ni = 0; ni < 4; ++ni) {
            int mg = m0 + wn * 64 + ni * 16 + (l & 15);
            int   i0 = __float_as_int(ra[ni].x);
            int   i1 = __float_as_int(ra[ni].y);
            int   i2 = __float_as_int(ra[ni].z);
            float w0 = ra[ni].w, w1 = rb[ni].x, w2 = rb[ni].y;
            const float4* g0 = (const float4*)(f1t + ((size_t)b * N_ + i0) * COUT_ + c0 + wc * 32 + lc);
            const float4* g1 = (const float4*)(f1t + ((size_t)b * N_ + i1) * COUT_ + c0 + wc * 32 + lc);
            const float4* g2 = (const float4*)(f1t + ((size_t)b * N_ + i2) * COUT_ + c0 + wc * 32 + lc);
            #pragma unroll
            for (int ci = 0; ci < 2; ++ci) {
                float4 G0 = g0[ci * 4];
                float4 G1 = g1[ci * 4];
                float4 G2 = g2[ci * 4];
                const float* f0 = (const float*)&G0;
                const float* f1 = (const float*)&G1;
                const float* f2 = (const float*)&G2;
                #pragma unroll
                for (int r = 0; r < 4; ++r) {
                    float v = fmaxf(acc[ci][ni][r] * scA[ci][r] + shA[ci][r], 0.f);
                    v = fmaf(w0, f0[r], v);
                    v = fmaf(w1, f1[r], v);
                    v = fmaf(w2, f2[r], v);
                    int c = c0 + wc * 32 + ci * 16 + lc + r;
                    dst[((size_t)b * COUT_ + c) * M_ + mg] = v;
                }
            }
        }
    }
}

__global__ __launch_bounds__(256) void up_kernel(
    const float* __restrict__ x1, const float* __restrict__ w_up,
    const float* __restrict__ g_up, const float* __restrict__ b_up,
    const float* __restrict__ m_up, const float* __restrict__ v_up,
    float* __restrict__ f1t)
{
    __shared__ float4 raw4[1056];
    gemm_body<CIN_, 0>((char*)raw4, blockIdx.z, blockIdx.y * 64, blockIdx.x * 128,
                       x1, w_up, g_up, b_up, m_up, v_up, f1t,
                       nullptr, nullptr, N_);
}

__global__ __launch_bounds__(256) void lat_kernel(
    const float* __restrict__ x2, const float* __restrict__ w_lat,
    const float* __restrict__ g_lat, const float* __restrict__ b_lat,
    const float* __restrict__ m_lat, const float* __restrict__ v_lat,
    const float* __restrict__ f1t, const float* __restrict__ nnrec,
    float* __restrict__ out0)
{
    __shared__ float4 raw4[960];
    gemm_body<COUT_, 1>((char*)raw4, blockIdx.z, blockIdx.y * 64, blockIdx.x * 128,
                        x2, w_lat, g_lat, b_lat, m_lat, v_lat, out0,
                        f1t, nnrec, M_);
}

// ---------------------------------------------------------------------------
// three_nn (round-10/17 EXACT structure — best measured: 50.5us steady,
// VALUBusy 73%): 8 lanes/query over disjoint 256-candidate segments; chunks
// of 8 read as b128 from padded LDS with REGISTER PING-PONG prefetch; single
// branchless bubble-insert chain per lane (ascending scan -> strict < is
// stable); butterfly merge with lexicographic (d2, idx). d^2 bits identical
// to the validated formula:
//   s = fma(z,z, fma(y,y, x*x)); dot likewise; d2 = max(fma(-2,dot,s2+s1),0)
// Failed alternatives (measured): ILP chains r11/r13 (57.5/67-71us), grid
// r12/r15/r16 (172/82.8/75.3us), 16-lane reshape r18 (63.3us — broke the
// 8-lane broadcast read pattern). This structure is the working point.
// ---------------------------------------------------------------------------
__device__ __forceinline__ void lex_insert(float e, int j,
    float& D0, float& D1, float& D2, int& I0, int& I1, int& I2)
{
    bool l0 = (e < D0) || (e == D0 && j < I0);
    bool l1 = (e < D1) || (e == D1 && j < I1);
    bool l2 = (e < D2) || (e == D2 && j < I2);
    if (l2) {
        if (l0)      { D2=D1; I2=I1; D1=D0; I1=I0; D0=e; I0=j; }
        else if (l1) { D2=D1; I2=I1; D1=e;  I1=j; }
        else         { D2=e;  I2=j; }
    }
}

__device__ __forceinline__ void bubble_insert(float e, int ie,
    float& D0, float& D1, float& D2, int& I0, int& I1, int& I2)
{
    bool l2 = e < D2;
    D2 = l2 ? e  : D2;
    I2 = l2 ? ie : I2;
    bool s1 = D2 < D1;
    float tf = D1; int ti = I1;
    D1 = s1 ? D2 : D1;  I1 = s1 ? I2 : I1;
    D2 = s1 ? tf : D2;  I2 = s1 ? ti : I2;
    bool s0 = D1 < D0;
    tf = D0; ti = I0;
    D0 = s0 ? D1 : D0;  I0 = s0 ? I1 : I0;
    D1 = s0 ? tf : D1;  I1 = s0 ? ti : I1;
}

__global__ __launch_bounds__(256) void three_nn_kernel(
    const float* __restrict__ p1, const float* __restrict__ p2,
    float* __restrict__ nnrec, float* __restrict__ out1)
{
    __shared__ float4 P[8][257];
    const int b = blockIdx.y;
    #pragma unroll
    for (int r = 0; r < 8; ++r) {
        int n = r * 256 + threadIdx.x;
        float x = p1[((size_t)(b*N_)+n)*3 + 0];
        float y = p1[((size_t)(b*N_)+n)*3 + 1];
        float z = p1[((size_t)(b*N_)+n)*3 + 2];
        float t = x * x;
        t = fmaf(y, y, t);
        t = fmaf(z, z, t);
        P[r][threadIdx.x] = make_float4(x, y, z, t);
    }
    __syncthreads();

    const int m = blockIdx.x * 32 + (threadIdx.x >> 3);
    const int s = threadIdx.x & 7;
    const size_t pbase = ((size_t)(b*M_) + m) * 3;
    const float qx = p2[pbase+0], qy = p2[pbase+1], qz = p2[pbase+2];
    float s2 = qx * qx;
    s2 = fmaf(qy, qy, s2);
    s2 = fmaf(qz, qz, s2);

    float D0 = FLT_MAX, D1 = FLT_MAX, D2 = FLT_MAX;
    int   I0 = 0x7fffffff, I1 = 0x7fffffff, I2 = 0x7fffffff;
    const int base = s * 256;
    const float4* Ps = &P[s][0];

    float4 ca[8], cb[8];
    #pragma unroll
    for (int u = 0; u < 8; ++u) ca[u] = Ps[u];

    #define PROC(CV, IB)                                                     \
        {                                                                    \
            float d[8];                                                      \
            _Pragma("unroll")                                                \
            for (int u = 0; u < 8; ++u) {                                    \
                float dot = qx * CV[u].x;                                    \
                dot = fmaf(qy, CV[u].y, dot);                                \
                dot = fmaf(qz, CV[u].z, dot);                                \
                float d2 = fmaf(-2.0f, dot, s2 + CV[u].w);                   \
                d[u] = fmaxf(d2, 0.0f);                                      \
            }                                                                \
            _Pragma("unroll")                                                \
            for (int u = 0; u < 8; ++u)                                      \
                bubble_insert(d[u], (IB) + u, D0, D1, D2, I0, I1, I2);       \
        }

    for (int j = 0; j < 32; j += 2) {
        #pragma unroll
        for (int u = 0; u < 8; ++u) cb[u] = Ps[(j + 1) * 8 + u];
        PROC(ca, base + j * 8);
        if (j + 2 < 32) {
            #pragma unroll
            for (int u = 0; u < 8; ++u) ca[u] = Ps[(j + 2) * 8 + u];
        }
        PROC(cb, base + (j + 1) * 8);
    }
    #undef PROC

    #pragma unroll
    for (int st = 1; st <= 4; st <<= 1) {
        float E0 = __shfl_xor(D0, st), E1 = __shfl_xor(D1, st), E2 = __shfl_xor(D2, st);
        int   J0 = __shfl_xor(I0, st), J1 = __shfl_xor(I1, st), J2 = __shfl_xor(I2, st);
        lex_insert(E0, J0, D0, D1, D2, I0, I1, I2);
        lex_insert(E1, J1, D0, D1, D2, I0, I1, I2);
        lex_insert(E2, J2, D0, D1, D2, I0, I1, I2);
    }
    if (s == 0) {
        float r0 = 1.0f / (D0 + 1e-8f);
        float r1 = 1.0f / (D1 + 1e-8f);
        float r2 = 1.0f / (D2 + 1e-8f);
        float sum = (r0 + r1) + r2;
        float* rp = nnrec + ((size_t)(b*M_) + m) * 8;
        ws_store_u32((int*)rp + 0, I0);
        ws_store_u32((int*)rp + 1, I1);
        ws_store_u32((int*)rp + 2, I2);
        ws_store_f32(rp + 3, r0 / sum);
        ws_store_f32(rp + 4, r1 / sum);
        ws_store_f32(rp + 5, r2 / sum);
        size_t o = ((size_t)(b*M_) + m) * 3;
        out1[o+0] = qx; out1[o+1] = qy; out1[o+2] = qz;
    }
}

// ---------------------------------------------------------------------------
extern "C" void kernel_launch(void* const* d_in, const int* in_sizes, int n_in,
                              void* d_out, int out_size, void* d_ws, size_t ws_size,
                              hipStream_t stream)
{
    (void)in_sizes; (void)n_in; (void)out_size; (void)ws_size;

    const float* x1    = (const float*)d_in[0];
    const float* p1    = (const float*)d_in[1];
    const float* x2    = (const float*)d_in[2];
    const float* p2    = (const float*)d_in[3];
    const float* w_up  = (const float*)d_in[4];
    const float* g_up  = (const float*)d_in[5];
    const float* b_up  = (const float*)d_in[6];
    const float* m_up  = (const float*)d_in[7];
    const float* v_up  = (const float*)d_in[8];
    const float* w_lat = (const float*)d_in[9];
    const float* g_lat = (const float*)d_in[10];
    const float* b_lat = (const float*)d_in[11];
    const float* m_lat = (const float*)d_in[12];
    const float* v_lat = (const float*)d_in[13];

    float* out0 = (float*)d_out;
    float* out1 = out0 + (size_t)B_ * COUT_ * M_;   // p2 passthrough

    // workspace layout: f1t (8 MB) | nnrec (1 MB, 8 floats per query)
    float* f1t   = (float*)d_ws;
    float* nnrec = f1t + (size_t)B_ * N_ * COUT_;

    up_kernel<<<dim3(N_ / 128, COUT_ / 64, B_), 256, 0, stream>>>(
        x1, w_up, g_up, b_up, m_up, v_up, f1t);

    three_nn_kernel<<<dim3(M_ / 32, B_), 256, 0, stream>>>(
        p1, p2, nnrec, out1);

    inv_kernel<<<dim3(512), 64, 0, stream>>>();

    lat_kernel<<<dim3(M_ / 128, COUT_ / 64, B_), 256, 0, stream>>>(
        x2, w_lat, g_lat, b_lat, m_lat, v_lat, f1t, nnrec, out0);
}